// Round 1
// baseline (324.041 us; speedup 1.0000x reference)
//
#include <hip/hip_runtime.h>
#include <hip/hip_bf16.h>

// Problem constants
#define BATCH 2
#define SEQ   4096
#define CHN   1024
#define NH    8
#define HD    128
#define NQROWS (BATCH*SEQ)   // 8192
#define QKVN  (3*CHN)        // 3072
#define NOFF  14             // telescope offsets: 0,1,2,4,...,4096
#define KCONV 7
#define NCH   16             // S-chunks per (b,h) for KV partial reduction
#define CHS   (SEQ/NCH)      // 256

typedef short bf16x8v __attribute__((ext_vector_type(8)));
typedef float f32x4v  __attribute__((ext_vector_type(4)));

__device__ __forceinline__ float b2f(short s) {
    return __uint_as_float(((unsigned)(unsigned short)s) << 16);
}
__device__ __forceinline__ unsigned short f2bu(float f) {
    __hip_bfloat16 h = __float2bfloat16(f);
    return *reinterpret_cast<unsigned short*>(&h);
}
// async global->LDS, 16B per lane; LDS dest = wave-uniform base + lane*16
__device__ __forceinline__ void gload16(const void* g, void* l) {
    __builtin_amdgcn_global_load_lds(
        (const __attribute__((address_space(1))) unsigned int*)g,
        (__attribute__((address_space(3))) unsigned int*)l, 16, 0, 0);
}

// ---------------- K1: f32 -> bf16 convert (vectorized) ----------------
__global__ void k_cvt(const float* __restrict__ in, short* __restrict__ out, int n4) {
    int i = blockIdx.x * blockDim.x + threadIdx.x;
    int stride = gridDim.x * blockDim.x;
    for (; i < n4; i += stride) {
        float4 v = reinterpret_cast<const float4*>(in)[i];
        ushort4 o;
        o.x = f2bu(v.x); o.y = f2bu(v.y); o.z = f2bu(v.z); o.w = f2bu(v.w);
        reinterpret_cast<ushort4*>(out)[i] = o;
    }
}

// ---------------- K2: f32 (R x Cc) -> bf16 transpose (Cc x R) ----------------
__global__ void k_transpose_cvt(const float* __restrict__ in, short* __restrict__ out,
                                int R, int Cc) {
    __shared__ float tile[32][33];
    int bc = blockIdx.x * 32, br = blockIdx.y * 32;
    int tx = threadIdx.x & 31, ty = threadIdx.x >> 5; // 32x8
    for (int i = 0; i < 32; i += 8)
        tile[ty + i][tx] = in[(size_t)(br + ty + i) * Cc + bc + tx];
    __syncthreads();
    for (int i = 0; i < 32; i += 8)
        out[(size_t)(bc + ty + i) * R + br + tx] = (short)f2bu(tile[tx][ty + i]);
}

// ---------------- GEMM: C[M,N] = A[M,K] @ Bt[N,K]^T  (all bf16, f32 acc) ----------
// m97 structure: 128x128 tile, BK=32, 4 waves (2x2 of 64x64), global_load_lds w=16.
// EPI=0: store bf16 into Cb.   EPI=1: store f32 Cf = resid + acc.
template<int EPI>
__global__ __launch_bounds__(256)
void k_gemm_bt(const short* __restrict__ A, const short* __restrict__ Bt,
               short* __restrict__ Cb, float* __restrict__ Cf,
               const float* __restrict__ resid, int M, int N, int K) {
    __shared__ short As[128 * 32];
    __shared__ short Bs[128 * 32];
    int tid = threadIdx.x;
    int w = tid >> 6, lane = tid & 63;
    int nbn = N >> 7;
    int bm = blockIdx.x / nbn, bn = blockIdx.x % nbn;
    size_t m0 = (size_t)bm << 7, n0 = (size_t)bn << 7;
    int wr = (w >> 1) << 6, wc = (w & 1) << 6;
    int lr = lane & 15, lk = lane >> 4;
    f32x4v acc[4][4] = {};

    int f0 = w * 64 + lane, f1 = f0 + 256;
    int r0 = f0 >> 2, q0 = f0 & 3;
    int r1 = f1 >> 2, q1 = f1 & 3;
    const short* Ap0 = A + (m0 + r0) * K + q0 * 8;
    const short* Ap1 = A + (m0 + r1) * K + q1 * 8;
    const short* Bp0 = Bt + (n0 + r0) * K + q0 * 8;
    const short* Bp1 = Bt + (n0 + r1) * K + q1 * 8;
    short* Asl0 = As + (w * 64) * 8;
    short* Asl1 = As + (256 + w * 64) * 8;
    short* Bsl0 = Bs + (w * 64) * 8;
    short* Bsl1 = Bs + (256 + w * 64) * 8;

    for (int k0 = 0; k0 < K; k0 += 32) {
        gload16(Ap0 + k0, Asl0);
        gload16(Ap1 + k0, Asl1);
        gload16(Bp0 + k0, Bsl0);
        gload16(Bp1 + k0, Bsl1);
        __syncthreads();
        bf16x8v af[4], bfv[4];
        #pragma unroll
        for (int m = 0; m < 4; ++m)
            af[m] = *reinterpret_cast<const bf16x8v*>(As + (wr + m * 16 + lr) * 32 + lk * 8);
        #pragma unroll
        for (int n = 0; n < 4; ++n)
            bfv[n] = *reinterpret_cast<const bf16x8v*>(Bs + (wc + n * 16 + lr) * 32 + lk * 8);
        #pragma unroll
        for (int m = 0; m < 4; ++m)
            #pragma unroll
            for (int n = 0; n < 4; ++n)
                acc[m][n] = __builtin_amdgcn_mfma_f32_16x16x32_bf16(af[m], bfv[n], acc[m][n], 0, 0, 0);
        __syncthreads();
    }
    // epilogue: C row = (lane>>4)*4 + i, col = lane&15 within each 16x16 fragment
    #pragma unroll
    for (int m = 0; m < 4; ++m) {
        size_t grow = m0 + wr + m * 16 + lk * 4;
        #pragma unroll
        for (int n = 0; n < 4; ++n) {
            size_t gcol = n0 + wc + n * 16 + lr;
            #pragma unroll
            for (int i = 0; i < 4; ++i) {
                size_t idx = (grow + i) * N + gcol;
                if (EPI == 0) Cb[idx] = (short)f2bu(acc[m][n][i]);
                else          Cf[idx] = resid[idx] + acc[m][n][i];
            }
        }
    }
}

// ---------------- K5: partial KV = sum_s fk(s)⊗v(s), partial ksum ----------------
// grid: 16 (b,h) * NCH chunks.  Vector-ALU version (round 1).
__global__ __launch_bounds__(256)
void k_kvpart(const short* __restrict__ qkv, float* __restrict__ kvpart,
              float* __restrict__ kspart) {
    __shared__ float fk_lds[32 * 128]; // 16 KB
    __shared__ short v_lds[32 * 128];  // 8 KB
    int t = threadIdx.x;
    int w = t >> 6, lane = t & 63;
    int bid = blockIdx.x;
    int bh = bid / NCH, ch = bid % NCH;
    int b = bh >> 3, h = bh & 7;
    size_t rowbase = (size_t)b * SEQ + (size_t)ch * CHS;
    int d0 = (t >> 4) * 8, e0 = (t & 15) * 8;
    float kv[8][8] = {};
    float ks[8] = {};
    for (int sub = 0; sub < CHS / 32; ++sub) {
        #pragma unroll
        for (int j = 0; j < 2; ++j) {  // stage fk (elu(k)+1, f32)
            int f = j * 256 + t;
            int row = f >> 4, c0 = (f & 15) * 8;
            const short* kp = qkv + (rowbase + sub * 32 + row) * QKVN + CHN + h * HD + c0;
            bf16x8v k8 = *reinterpret_cast<const bf16x8v*>(kp);
            float* dst = fk_lds + row * 128 + c0;
            #pragma unroll
            for (int e = 0; e < 8; ++e) {
                float x = b2f(k8[e]);
                dst[e] = x > 0.f ? x + 1.f : __expf(x);
            }
        }
        #pragma unroll
        for (int j = 0; j < 2; ++j) {  // stage v (bf16, async)
            int f = j * 256 + w * 64 + lane;
            int row = f >> 4, c0 = (f & 15) * 8;
            gload16(qkv + (rowbase + sub * 32 + row) * QKVN + 2 * CHN + h * HD + c0,
                    v_lds + (j * 256 + w * 64) * 8);
        }
        __syncthreads();
        for (int ss = 0; ss < 32; ++ss) {
            float fa[8];
            *(float4*)&fa[0] = *(const float4*)&fk_lds[ss * 128 + d0];
            *(float4*)&fa[4] = *(const float4*)&fk_lds[ss * 128 + d0 + 4];
            bf16x8v vv = *reinterpret_cast<const bf16x8v*>(&v_lds[ss * 128 + e0]);
            float vb[8];
            #pragma unroll
            for (int e = 0; e < 8; ++e) vb[e] = b2f(vv[e]);
            #pragma unroll
            for (int i = 0; i < 8; ++i) {
                ks[i] += fa[i];
                #pragma unroll
                for (int e = 0; e < 8; ++e) kv[i][e] += fa[i] * vb[e];
            }
        }
        __syncthreads();
    }
    size_t obase = (size_t)bid * (128 * 128);
    #pragma unroll
    for (int i = 0; i < 8; ++i) {
        *(float4*)&kvpart[obase + (d0 + i) * 128 + e0]     = *(float4*)&kv[i][0];
        *(float4*)&kvpart[obase + (d0 + i) * 128 + e0 + 4] = *(float4*)&kv[i][4];
    }
    if ((t & 15) == 0)
        #pragma unroll
        for (int i = 0; i < 8; ++i)
            kspart[(size_t)bid * 128 + d0 + i] = ks[i];
}

// ---------------- K6: reduce partials; store KV^T (bf16) + ksum (f32) ----------------
__global__ void k_kvreduce(const float* __restrict__ kvpart, const float* __restrict__ kspart,
                           short* __restrict__ kvt, float* __restrict__ ksum) {
    int idx = blockIdx.x * blockDim.x + threadIdx.x;
    const int total_kv = 16 * 128 * 128;
    if (idx < total_kv) {
        int bh = idx >> 14;
        int r = idx & 16383;          // d*128 + e
        int d = r >> 7, e = r & 127;
        float s = 0.f;
        const float* p = kvpart + (size_t)bh * NCH * 16384 + r;
        #pragma unroll
        for (int c = 0; c < NCH; ++c) s += p[(size_t)c * 16384];
        kvt[((size_t)bh << 14) + e * 128 + d] = (short)f2bu(s);  // transposed store
    } else {
        int k = idx - total_kv;
        if (k < 16 * 128) {
            int bh = k >> 7, d = k & 127;
            float s = 0.f;
            const float* p = kspart + (size_t)bh * NCH * 128 + d;
            #pragma unroll
            for (int c = 0; c < NCH; ++c) s += p[c * 128];
            ksum[k] = s;
        }
    }
}

// ---------------- K7: fused middle: telescope attn + conv + linear attn -> h (bf16) ----
// block = (b,h, 32-row s-chunk); 256 threads
__global__ __launch_bounds__(256)
void k_middle(const short* __restrict__ qkv, const short* __restrict__ kvt,
              const float* __restrict__ ksum, const float* __restrict__ conv_w,
              short* __restrict__ hbuf) {
    __shared__ short kvt_lds[128 * 128];  // 32 KB  KV^T[e][d] bf16
    __shared__ short q_lds[32 * 128];     // 8 KB
    __shared__ short fq_lds[32 * 128];    // 8 KB
    __shared__ float low_lds[32 * 128];   // 16 KB
    __shared__ float ksum_lds[128];
    __shared__ float cw_lds[128 * KCONV];
    int t = threadIdx.x;
    int w = t >> 6, lane = t & 63;
    int bid = blockIdx.x;
    int bh = bid >> 7, chunk = bid & 127;
    int b = bh >> 3, h = bh & 7;
    int s0 = chunk * 32;
    size_t rowbase = (size_t)b * SEQ;

    { // stage KV^T (linear 32KB copy)
        const short* src = kvt + ((size_t)bh << 14);
        #pragma unroll
        for (int j = 0; j < 8; ++j) {
            int f = j * 256 + w * 64;
            gload16(src + (size_t)(f + lane) * 8, kvt_lds + (size_t)f * 8);
        }
    }
    { // stage q rows (raw)
        #pragma unroll
        for (int j = 0; j < 2; ++j) {
            int f = j * 256 + w * 64 + lane;
            int row = f >> 4, c0 = (f & 15) * 8;
            gload16(qkv + (rowbase + s0 + row) * QKVN + h * HD + c0,
                    q_lds + (size_t)(j * 256 + w * 64) * 8);
        }
    }
    if (t < 128) ksum_lds[t] = ksum[bh * 128 + t];
    for (int f = t; f < 128 * KCONV; f += 256) {
        int d = f / KCONV, j = f % KCONV;
        cw_lds[f] = conv_w[(h * HD + d) * KCONV + j];
    }
    __syncthreads();
    // fq = elu(q)+1 in bf16
    #pragma unroll
    for (int j = 0; j < 2; ++j) {
        int f = j * 256 + t;
        bf16x8v qv8 = *reinterpret_cast<const bf16x8v*>(q_lds + f * 8);
        bf16x8v fq8;
        #pragma unroll
        for (int e = 0; e < 8; ++e) {
            float x = b2f(qv8[e]);
            float fx = x > 0.f ? x + 1.f : __expf(x);
            fq8[e] = (short)f2bu(fx);
        }
        *reinterpret_cast<bf16x8v*>(fq_lds + f * 8) = fq8;
    }
    __syncthreads();
    // MFMA: low_num(32x128) = fq(32x128) @ KV(128x128); wave w owns e-range w*32..+32
    {
        int lr = lane & 15, lk = lane >> 4;
        f32x4v lacc[2][2] = {};
        #pragma unroll
        for (int ksb = 0; ksb < 4; ++ksb) {
            bf16x8v af[2], bfv[2];
            #pragma unroll
            for (int m = 0; m < 2; ++m)
                af[m] = *reinterpret_cast<const bf16x8v*>(fq_lds + (m * 16 + lr) * 128 + ksb * 32 + lk * 8);
            #pragma unroll
            for (int n = 0; n < 2; ++n)
                bfv[n] = *reinterpret_cast<const bf16x8v*>(kvt_lds + (w * 32 + n * 16 + lr) * 128 + ksb * 32 + lk * 8);
            #pragma unroll
            for (int m = 0; m < 2; ++m)
                #pragma unroll
                for (int n = 0; n < 2; ++n)
                    lacc[m][n] = __builtin_amdgcn_mfma_f32_16x16x32_bf16(af[m], bfv[n], lacc[m][n], 0, 0, 0);
        }
        #pragma unroll
        for (int m = 0; m < 2; ++m)
            #pragma unroll
            for (int n = 0; n < 2; ++n)
                #pragma unroll
                for (int i = 0; i < 4; ++i)
                    low_lds[(m * 16 + lk * 4 + i) * 128 + w * 32 + n * 16 + lr] = lacc[m][n][i];
    }
    // vector phase: 8 threads per s-row, 16 channels each
    int row = t >> 3, j8 = t & 7;
    int e0 = j8 * 16;
    int sl = s0 + row;
    // z = fq . ksum (partial over this thread's 16 dims, reduce across 8 lanes)
    float zp = 0.f;
    #pragma unroll
    for (int d = 0; d < 16; ++d)
        zp += b2f(fq_lds[row * 128 + e0 + d]) * ksum_lds[e0 + d];
    zp += __shfl_xor(zp, 1); zp += __shfl_xor(zp, 2); zp += __shfl_xor(zp, 4);
    float z = zp + 1e-6f;
    // raw q for telescope dots
    float qv[16];
    #pragma unroll
    for (int d = 0; d < 16; ++d) qv[d] = b2f(q_lds[row * 128 + e0 + d]);
    // telescope scores
    float scb[NOFF];
    #pragma unroll
    for (int o = 0; o < NOFF; ++o) {
        int off = (o == 0) ? 0 : (1 << (o - 1));
        int p = sl - off;
        float acc = 0.f;
        if (p >= 0) {
            const short* kp = qkv + (rowbase + p) * QKVN + CHN + h * HD + e0;
            bf16x8v k0v = *(const bf16x8v*)kp;
            bf16x8v k1v = *(const bf16x8v*)(kp + 8);
            #pragma unroll
            for (int d = 0; d < 8; ++d) acc += qv[d] * b2f(k0v[d]);
            #pragma unroll
            for (int d = 0; d < 8; ++d) acc += qv[8 + d] * b2f(k1v[d]);
        }
        scb[o] = acc;
    }
    #pragma unroll
    for (int o = 0; o < NOFF; ++o) {
        float v = scb[o];
        v += __shfl_xor(v, 1); v += __shfl_xor(v, 2); v += __shfl_xor(v, 4);
        scb[o] = v * 0.08838834764831845f;  // 1/sqrt(128)
    }
    float mmax = -1e30f;
    #pragma unroll
    for (int o = 0; o < NOFF; ++o) {
        int off = (o == 0) ? 0 : (1 << (o - 1));
        if (sl - off >= 0 && scb[o] > mmax) mmax = scb[o];
    }
    float wsum = 0.f;
    float tacc[16] = {};
    #pragma unroll
    for (int o = 0; o < NOFF; ++o) {
        int off = (o == 0) ? 0 : (1 << (o - 1));
        int p = sl - off;
        if (p < 0) continue;
        float wv = __expf(scb[o] - mmax);
        wsum += wv;
        const short* vp = qkv + (rowbase + p) * QKVN + 2 * CHN + h * HD + e0;
        bf16x8v v0 = *(const bf16x8v*)vp;
        bf16x8v v1 = *(const bf16x8v*)(vp + 8);
        #pragma unroll
        for (int d = 0; d < 8; ++d) tacc[d]     += wv * b2f(v0[d]);
        #pragma unroll
        for (int d = 0; d < 8; ++d) tacc[8 + d] += wv * b2f(v1[d]);
    }
    float inv_wsum = 1.f / wsum;
    // depthwise causal conv
    float cacc[16] = {};
    #pragma unroll
    for (int jj = 0; jj < KCONV; ++jj) {
        int p = sl - 6 + jj;
        if (p < 0) continue;
        const short* vp = qkv + (rowbase + p) * QKVN + 2 * CHN + h * HD + e0;
        bf16x8v v0 = *(const bf16x8v*)vp;
        bf16x8v v1 = *(const bf16x8v*)(vp + 8);
        #pragma unroll
        for (int d = 0; d < 8; ++d) cacc[d]     += b2f(v0[d]) * cw_lds[(e0 + d) * KCONV + jj];
        #pragma unroll
        for (int d = 0; d < 8; ++d) cacc[8 + d] += b2f(v1[d]) * cw_lds[(e0 + 8 + d) * KCONV + jj];
    }
    __syncthreads();  // low_lds ready
    short outv[16];
    #pragma unroll
    for (int d = 0; d < 16; ++d) {
        float hval = tacc[d] * inv_wsum + cacc[d] + low_lds[row * 128 + e0 + d] / z;
        outv[d] = (short)f2bu(hval);
    }
    bf16x8v* op = (bf16x8v*)(hbuf + (rowbase + sl) * CHN + h * HD + e0);
    op[0] = *(bf16x8v*)&outv[0];
    op[1] = *(bf16x8v*)&outv[8];
}

// ---------------- host launch ----------------
extern "C" void kernel_launch(void* const* d_in, const int* in_sizes, int n_in,
                              void* d_out, int out_size, void* d_ws, size_t ws_size,
                              hipStream_t stream) {
    const float* x      = (const float*)d_in[0];
    const float* Wqkv   = (const float*)d_in[1];
    const float* Wo     = (const float*)d_in[2];
    const float* conv_w = (const float*)d_in[3];
    float* out = (float*)d_out;

    char* ws = (char*)d_ws;
    size_t off = 0;
    auto alloc = [&](size_t bytes) {
        char* p = ws + off;
        off += (bytes + 255) & ~(size_t)255;
        return (void*)p;
    };
    short* xb     = (short*)alloc((size_t)NQROWS * CHN * 2);
    short* wqkvT  = (short*)alloc((size_t)QKVN * CHN * 2);
    short* woT    = (short*)alloc((size_t)CHN * CHN * 2);
    short* qkv    = (short*)alloc((size_t)NQROWS * QKVN * 2);
    short* hbuf   = (short*)alloc((size_t)NQROWS * CHN * 2);
    float* kvpart = (float*)alloc((size_t)16 * NCH * 128 * 128 * 4);
    float* kspart = (float*)alloc((size_t)16 * NCH * 128 * 4);
    short* kvt    = (short*)alloc((size_t)16 * 128 * 128 * 2);
    float* ksum   = (float*)alloc((size_t)16 * 128 * 4);

    // converts / transposes
    k_cvt<<<2048, 256, 0, stream>>>(x, xb, NQROWS * CHN / 4);
    k_transpose_cvt<<<dim3(QKVN / 32, CHN / 32), 256, 0, stream>>>(Wqkv, wqkvT, CHN, QKVN);
    k_transpose_cvt<<<dim3(CHN / 32, CHN / 32), 256, 0, stream>>>(Wo, woT, CHN, CHN);
    // GEMM1: qkv = xb @ Wqkv
    k_gemm_bt<0><<<(NQROWS / 128) * (QKVN / 128), 256, 0, stream>>>(
        xb, wqkvT, qkv, nullptr, nullptr, NQROWS, QKVN, CHN);
    // KV reduction (linear attention state)
    k_kvpart<<<16 * NCH, 256, 0, stream>>>(qkv, kvpart, kspart);
    k_kvreduce<<<(16 * 128 * 128 + 16 * 128) / 256, 256, 0, stream>>>(kvpart, kspart, kvt, ksum);
    // fused middle -> h
    k_middle<<<16 * 128, 256, 0, stream>>>(qkv, kvt, ksum, conv_w, hbuf);
    // GEMM2 + residual: out = x + h @ Wo
    k_gemm_bt<1><<<(NQROWS / 128) * (CHN / 128), 256, 0, stream>>>(
        hbuf, woT, nullptr, out, x, NQROWS, CHN, CHN);
}

// Round 4
// 297.632 us; speedup vs baseline: 1.0887x; 1.0887x over previous
//
#include <hip/hip_runtime.h>
#include <hip/hip_bf16.h>

// Problem constants
#define BATCH 2
#define SEQ   4096
#define CHN   1024
#define NH    8
#define HD    128
#define NQROWS (BATCH*SEQ)   // 8192
#define QKVN  (3*CHN)        // 3072
#define NOFF  14             // telescope offsets: 0,1,2,4,...,4096
#define KCONV 7
#define NCH   16             // S-chunks per (b,h) for KV partial reduction
#define CHS   (SEQ/NCH)      // 256

typedef short bf16x8v __attribute__((ext_vector_type(8)));
typedef short bf16x4v __attribute__((ext_vector_type(4)));
typedef float f32x4v  __attribute__((ext_vector_type(4)));

__device__ __forceinline__ float b2f(short s) {
    return __uint_as_float(((unsigned)(unsigned short)s) << 16);
}
__device__ __forceinline__ unsigned short f2bu(float f) {
    __hip_bfloat16 h = __float2bfloat16(f);
    return *reinterpret_cast<unsigned short*>(&h);
}
// async global->LDS, 16B per lane; LDS dest = wave-uniform base + lane*16
__device__ __forceinline__ void gload16(const void* g, void* l) {
    __builtin_amdgcn_global_load_lds(
        (const __attribute__((address_space(1))) unsigned int*)g,
        (__attribute__((address_space(3))) unsigned int*)l, 16, 0, 0);
}

// ---------------- K1: f32 -> bf16 convert (vectorized) ----------------
__global__ void k_cvt(const float* __restrict__ in, short* __restrict__ out, int n4) {
    int i = blockIdx.x * blockDim.x + threadIdx.x;
    int stride = gridDim.x * blockDim.x;
    for (; i < n4; i += stride) {
        float4 v = reinterpret_cast<const float4*>(in)[i];
        ushort4 o;
        o.x = f2bu(v.x); o.y = f2bu(v.y); o.z = f2bu(v.z); o.w = f2bu(v.w);
        reinterpret_cast<ushort4*>(out)[i] = o;
    }
}

// ---------------- K2: f32 (R x Cc) -> bf16 transpose (Cc x R) ----------------
__global__ void k_transpose_cvt(const float* __restrict__ in, short* __restrict__ out,
                                int R, int Cc) {
    __shared__ float tile[32][33];
    int bc = blockIdx.x * 32, br = blockIdx.y * 32;
    int tx = threadIdx.x & 31, ty = threadIdx.x >> 5; // 32x8
    for (int i = 0; i < 32; i += 8)
        tile[ty + i][tx] = in[(size_t)(br + ty + i) * Cc + bc + tx];
    __syncthreads();
    for (int i = 0; i < 32; i += 8)
        out[(size_t)(bc + ty + i) * R + br + tx] = (short)f2bu(tile[tx][ty + i]);
}

// ---------------- GEMM: C[M,N] = A[M,K] @ Bt[N,K]^T  (all bf16, f32 acc) ----------
// m97 structure: 128x128 tile, BK=32, 4 waves (2x2 of 64x64), global_load_lds w=16.
// EPI=0: store bf16 into Cb.   EPI=1: store f32 Cf = resid + acc.
template<int EPI>
__global__ __launch_bounds__(256)
void k_gemm_bt(const short* __restrict__ A, const short* __restrict__ Bt,
               short* __restrict__ Cb, float* __restrict__ Cf,
               const float* __restrict__ resid, int M, int N, int K) {
    __shared__ short As[128 * 32];
    __shared__ short Bs[128 * 32];
    int tid = threadIdx.x;
    int w = tid >> 6, lane = tid & 63;
    int nbn = N >> 7;
    int bm = blockIdx.x / nbn, bn = blockIdx.x % nbn;
    size_t m0 = (size_t)bm << 7, n0 = (size_t)bn << 7;
    int wr = (w >> 1) << 6, wc = (w & 1) << 6;
    int lr = lane & 15, lk = lane >> 4;
    f32x4v acc[4][4] = {};

    int f0 = w * 64 + lane, f1 = f0 + 256;
    int r0 = f0 >> 2, q0 = f0 & 3;
    int r1 = f1 >> 2, q1 = f1 & 3;
    const short* Ap0 = A + (m0 + r0) * K + q0 * 8;
    const short* Ap1 = A + (m0 + r1) * K + q1 * 8;
    const short* Bp0 = Bt + (n0 + r0) * K + q0 * 8;
    const short* Bp1 = Bt + (n0 + r1) * K + q1 * 8;
    short* Asl0 = As + (w * 64) * 8;
    short* Asl1 = As + (256 + w * 64) * 8;
    short* Bsl0 = Bs + (w * 64) * 8;
    short* Bsl1 = Bs + (256 + w * 64) * 8;

    for (int k0 = 0; k0 < K; k0 += 32) {
        gload16(Ap0 + k0, Asl0);
        gload16(Ap1 + k0, Asl1);
        gload16(Bp0 + k0, Bsl0);
        gload16(Bp1 + k0, Bsl1);
        __syncthreads();
        bf16x8v af[4], bfv[4];
        #pragma unroll
        for (int m = 0; m < 4; ++m)
            af[m] = *reinterpret_cast<const bf16x8v*>(As + (wr + m * 16 + lr) * 32 + lk * 8);
        #pragma unroll
        for (int n = 0; n < 4; ++n)
            bfv[n] = *reinterpret_cast<const bf16x8v*>(Bs + (wc + n * 16 + lr) * 32 + lk * 8);
        #pragma unroll
        for (int m = 0; m < 4; ++m)
            #pragma unroll
            for (int n = 0; n < 4; ++n)
                acc[m][n] = __builtin_amdgcn_mfma_f32_16x16x32_bf16(af[m], bfv[n], acc[m][n], 0, 0, 0);
        __syncthreads();
    }
    // epilogue: C row = (lane>>4)*4 + i, col = lane&15 within each 16x16 fragment
    #pragma unroll
    for (int m = 0; m < 4; ++m) {
        size_t grow = m0 + wr + m * 16 + lk * 4;
        #pragma unroll
        for (int n = 0; n < 4; ++n) {
            size_t gcol = n0 + wc + n * 16 + lr;
            #pragma unroll
            for (int i = 0; i < 4; ++i) {
                size_t idx = (grow + i) * N + gcol;
                if (EPI == 0) Cb[idx] = (short)f2bu(acc[m][n][i]);
                else          Cf[idx] = resid[idx] + acc[m][n][i];
            }
        }
    }
}

// ---------------- K5: partial KV = sum_s fk(s)⊗v(s), partial ksum ----------------
// grid: 16 (b,h) * NCH chunks * 2 e-halves.  512 blocks -> 2/CU for latency hiding.
__global__ __launch_bounds__(256)
void k_kvpart(const short* __restrict__ qkv, float* __restrict__ kvpart,
              float* __restrict__ kspart) {
    __shared__ float fk_lds[32 * 128]; // 16 KB
    __shared__ short v_lds[32 * 64];   // 4 KB (this block's e-half)
    int t = threadIdx.x;
    int w = t >> 6, lane = t & 63;
    int bid = blockIdx.x;              // ((bh*NCH)+ch)*2 + eh
    int eh = bid & 1;
    int ch = (bid >> 1) & (NCH - 1);
    int bh = bid / (NCH * 2);
    int b = bh >> 3, h = bh & 7;
    size_t rowbase = (size_t)b * SEQ + (size_t)ch * CHS;
    const short* kbase = qkv + CHN + h * HD;
    const short* vbase = qkv + 2 * CHN + h * HD + eh * 64;
    int d0 = (t >> 4) * 8;        // 16 groups x 8 = 128 d
    int e0l = (t & 15) * 4;       // local e in [0,64)
    float kv[8][4] = {};
    float ks[8] = {};
    for (int sub = 0; sub < CHS / 32; ++sub) {
        #pragma unroll
        for (int j = 0; j < 2; ++j) {  // stage fk (elu(k)+1, f32): 32 rows x 128 d
            int f = j * 256 + t;
            int row = f >> 4, c0 = (f & 15) * 8;
            bf16x8v k8 = *reinterpret_cast<const bf16x8v*>(
                kbase + (rowbase + sub * 32 + row) * QKVN + c0);
            float* dst = fk_lds + row * 128 + c0;
            #pragma unroll
            for (int e = 0; e < 8; ++e) {
                float x = b2f(k8[e]);
                dst[e] = x > 0.f ? x + 1.f : __expf(x);
            }
        }
        {   // stage v e-half (bf16, async): 32 rows x 64 e = 4KB = 256 lanes x 16B
            int f = w * 64 + lane;          // row = f>>3, c0 = (f&7)*8
            gload16(vbase + (rowbase + sub * 32 + (f >> 3)) * QKVN + (f & 7) * 8,
                    v_lds + (size_t)(w * 64) * 8);
        }
        __syncthreads();
        for (int ss = 0; ss < 32; ++ss) {
            float fa[8];
            *(float4*)&fa[0] = *(const float4*)&fk_lds[ss * 128 + d0];     // broadcast
            *(float4*)&fa[4] = *(const float4*)&fk_lds[ss * 128 + d0 + 4];
            bf16x4v vv = *reinterpret_cast<const bf16x4v*>(&v_lds[ss * 64 + e0l]);
            float vb[4];
            #pragma unroll
            for (int e = 0; e < 4; ++e) vb[e] = b2f(vv[e]);
            #pragma unroll
            for (int i = 0; i < 8; ++i) {
                ks[i] += fa[i];
                #pragma unroll
                for (int e = 0; e < 4; ++e) kv[i][e] += fa[i] * vb[e];
            }
        }
        __syncthreads();
    }
    size_t obase = (size_t)bid * (128 * 64);
    #pragma unroll
    for (int i = 0; i < 8; ++i)
        *(float4*)&kvpart[obase + (d0 + i) * 64 + e0l] = *(float4*)&kv[i][0];
    if ((t & 15) == 0 && eh == 0)
        #pragma unroll
        for (int i = 0; i < 8; ++i)
            kspart[(size_t)(bh * NCH + ch) * 128 + d0 + i] = ks[i];
}

// ---------------- K6: reduce partials; store KV^T (bf16) + ksum (f32) ----------------
__global__ void k_kvreduce(const float* __restrict__ kvpart, const float* __restrict__ kspart,
                           short* __restrict__ kvt, float* __restrict__ ksum) {
    int idx = blockIdx.x * blockDim.x + threadIdx.x;
    const int total_kv = 16 * 128 * 128;
    if (idx < total_kv) {
        int bh = idx >> 14;
        int r = idx & 16383;          // d*128 + e
        int d = r >> 7, e = r & 127;
        int ehalf = e >> 6, el = e & 63;
        float s = 0.f;
        const float* p = kvpart + ((size_t)(bh * NCH) * 2 + ehalf) * 8192 + d * 64 + el;
        #pragma unroll
        for (int c = 0; c < NCH; ++c) s += p[(size_t)c * 2 * 8192];
        kvt[((size_t)bh << 14) + e * 128 + d] = (short)f2bu(s);  // transposed store
    } else {
        int k = idx - total_kv;
        if (k < 16 * 128) {
            int bh = k >> 7, d = k & 127;
            float s = 0.f;
            const float* p = kspart + (size_t)bh * NCH * 128 + d;
            #pragma unroll
            for (int c = 0; c < NCH; ++c) s += p[c * 128];
            ksum[k] = s;
        }
    }
}

// ---------------- K7: fused middle: telescope attn + conv + linear attn -> h (bf16) ----
// block = (b,h, 32-row s-chunk); 256 threads.  v2: minimal LDS (28.6KB) for occupancy;
// kvt + q read straight from global (L2-hot), gathers from global (L2/L3).
__global__ __launch_bounds__(256)
void k_middle(const short* __restrict__ qkv, const short* __restrict__ kvt,
              const float* __restrict__ ksum, const float* __restrict__ conv_w,
              short* __restrict__ hbuf) {
    __shared__ short fq_lds[32 * 128];    // 8 KB
    __shared__ float low_lds[32 * 128];   // 16 KB
    __shared__ float ksum_lds[128];
    __shared__ float cw_lds[128 * KCONV]; // 3.5 KB
    int t = threadIdx.x;
    int w = t >> 6, lane = t & 63;
    int bid = blockIdx.x;
    int bh = bid >> 7, chunk = bid & 127;
    int b = bh >> 3, h = bh & 7;
    int s0 = chunk * 32;
    size_t rowbase = (size_t)b * SEQ;
    const short* qbase = qkv + h * HD;
    const short* kbase = qkv + CHN + h * HD;
    const short* vbase = qkv + 2 * CHN + h * HD;

    if (t < 128) ksum_lds[t] = ksum[bh * 128 + t];
    for (int f = t; f < 128 * KCONV; f += 256) {
        int d = f / KCONV, j = f % KCONV;
        cw_lds[f] = conv_w[(h * HD + d) * KCONV + j];
    }
    // fq = elu(q)+1 (bf16), q loaded directly from global
    #pragma unroll
    for (int j = 0; j < 2; ++j) {
        int f = j * 256 + t;
        int row = f >> 4, c0 = (f & 15) * 8;
        bf16x8v q8 = *reinterpret_cast<const bf16x8v*>(
            qbase + (rowbase + s0 + row) * QKVN + c0);
        bf16x8v fq8;
        #pragma unroll
        for (int e = 0; e < 8; ++e) {
            float x = b2f(q8[e]);
            float fx = x > 0.f ? x + 1.f : __expf(x);
            fq8[e] = (short)f2bu(fx);
        }
        *reinterpret_cast<bf16x8v*>(fq_lds + row * 128 + c0) = fq8;
    }
    __syncthreads();
    // MFMA: low_num(32x128) = fq(32x128) @ KV(128x128); wave w owns e-range w*32..+32.
    // B-fragments straight from global kvt (512KB total, L2-resident).
    {
        int lr = lane & 15, lk = lane >> 4;
        const short* kvg = kvt + ((size_t)bh << 14);
        f32x4v lacc[2][2] = {};
        #pragma unroll
        for (int ksb = 0; ksb < 4; ++ksb) {
            bf16x8v af[2], bfv[2];
            #pragma unroll
            for (int m = 0; m < 2; ++m)
                af[m] = *reinterpret_cast<const bf16x8v*>(fq_lds + (m * 16 + lr) * 128 + ksb * 32 + lk * 8);
            #pragma unroll
            for (int n = 0; n < 2; ++n)
                bfv[n] = *reinterpret_cast<const bf16x8v*>(kvg + (w * 32 + n * 16 + lr) * 128 + ksb * 32 + lk * 8);
            #pragma unroll
            for (int m = 0; m < 2; ++m)
                #pragma unroll
                for (int n = 0; n < 2; ++n)
                    lacc[m][n] = __builtin_amdgcn_mfma_f32_16x16x32_bf16(af[m], bfv[n], lacc[m][n], 0, 0, 0);
        }
        #pragma unroll
        for (int m = 0; m < 2; ++m)
            #pragma unroll
            for (int n = 0; n < 2; ++n)
                #pragma unroll
                for (int i = 0; i < 4; ++i)
                    low_lds[(m * 16 + lk * 4 + i) * 128 + w * 32 + n * 16 + lr] = lacc[m][n][i];
    }
    // vector phase: 8 threads per s-row, 16 channels each
    int row = t >> 3, j8 = t & 7;
    int e0 = j8 * 16;
    int sl = s0 + row;
    // z = fq . ksum (partial over 16 dims, reduce across 8 lanes)
    float zp = 0.f;
    #pragma unroll
    for (int d = 0; d < 16; ++d)
        zp += b2f(fq_lds[row * 128 + e0 + d]) * ksum_lds[e0 + d];
    zp += __shfl_xor(zp, 1); zp += __shfl_xor(zp, 2); zp += __shfl_xor(zp, 4);
    float z = zp + 1e-6f;
    // raw q for telescope dots (global, L2-hot)
    float qv[16];
    {
        const short* qp = qbase + (rowbase + sl) * QKVN + e0;
        bf16x8v q0 = *(const bf16x8v*)qp;
        bf16x8v q1 = *(const bf16x8v*)(qp + 8);
        #pragma unroll
        for (int d = 0; d < 8; ++d) { qv[d] = b2f(q0[d]); qv[8 + d] = b2f(q1[d]); }
    }
    // telescope scores
    float scb[NOFF];
    #pragma unroll
    for (int o = 0; o < NOFF; ++o) {
        int off = (o == 0) ? 0 : (1 << (o - 1));
        int p = sl - off;
        float acc = 0.f;
        if (p >= 0) {
            const short* kp = kbase + (rowbase + p) * QKVN + e0;
            bf16x8v k0v = *(const bf16x8v*)kp;
            bf16x8v k1v = *(const bf16x8v*)(kp + 8);
            #pragma unroll
            for (int d = 0; d < 8; ++d) acc += qv[d] * b2f(k0v[d]);
            #pragma unroll
            for (int d = 0; d < 8; ++d) acc += qv[8 + d] * b2f(k1v[d]);
        }
        scb[o] = acc;
    }
    #pragma unroll
    for (int o = 0; o < NOFF; ++o) {
        float v = scb[o];
        v += __shfl_xor(v, 1); v += __shfl_xor(v, 2); v += __shfl_xor(v, 4);
        scb[o] = v * 0.08838834764831845f;  // 1/sqrt(128)
    }
    float mmax = -1e30f;
    #pragma unroll
    for (int o = 0; o < NOFF; ++o) {
        int off = (o == 0) ? 0 : (1 << (o - 1));
        if (sl - off >= 0 && scb[o] > mmax) mmax = scb[o];
    }
    float wsum = 0.f;
    float tacc[16] = {};
    #pragma unroll
    for (int o = 0; o < NOFF; ++o) {
        int off = (o == 0) ? 0 : (1 << (o - 1));
        int p = sl - off;
        if (p < 0) continue;
        float wv = __expf(scb[o] - mmax);
        wsum += wv;
        const short* vp = vbase + (rowbase + p) * QKVN + e0;
        bf16x8v v0 = *(const bf16x8v*)vp;
        bf16x8v v1 = *(const bf16x8v*)(vp + 8);
        #pragma unroll
        for (int d = 0; d < 8; ++d) tacc[d]     += wv * b2f(v0[d]);
        #pragma unroll
        for (int d = 0; d < 8; ++d) tacc[8 + d] += wv * b2f(v1[d]);
    }
    float inv_wsum = 1.f / wsum;
    // depthwise causal conv
    float cacc[16] = {};
    #pragma unroll
    for (int jj = 0; jj < KCONV; ++jj) {
        int p = sl - 6 + jj;
        if (p < 0) continue;
        const short* vp = vbase + (rowbase + p) * QKVN + e0;
        bf16x8v v0 = *(const bf16x8v*)vp;
        bf16x8v v1 = *(const bf16x8v*)(vp + 8);
        #pragma unroll
        for (int d = 0; d < 8; ++d) cacc[d]     += b2f(v0[d]) * cw_lds[(e0 + d) * KCONV + jj];
        #pragma unroll
        for (int d = 0; d < 8; ++d) cacc[8 + d] += b2f(v1[d]) * cw_lds[(e0 + 8 + d) * KCONV + jj];
    }
    __syncthreads();  // low_lds ready
    short outv[16];
    #pragma unroll
    for (int d = 0; d < 16; ++d) {
        float hval = tacc[d] * inv_wsum + cacc[d] + low_lds[row * 128 + e0 + d] / z;
        outv[d] = (short)f2bu(hval);
    }
    bf16x8v* op = (bf16x8v*)(hbuf + (rowbase + sl) * CHN + h * HD + e0);
    op[0] = *(bf16x8v*)&outv[0];
    op[1] = *(bf16x8v*)&outv[8];
}

// ---------------- host launch ----------------
extern "C" void kernel_launch(void* const* d_in, const int* in_sizes, int n_in,
                              void* d_out, int out_size, void* d_ws, size_t ws_size,
                              hipStream_t stream) {
    const float* x      = (const float*)d_in[0];
    const float* Wqkv   = (const float*)d_in[1];
    const float* Wo     = (const float*)d_in[2];
    const float* conv_w = (const float*)d_in[3];
    float* out = (float*)d_out;

    char* ws = (char*)d_ws;
    size_t off = 0;
    auto alloc = [&](size_t bytes) {
        char* p = ws + off;
        off += (bytes + 255) & ~(size_t)255;
        return (void*)p;
    };
    short* xb     = (short*)alloc((size_t)NQROWS * CHN * 2);
    short* wqkvT  = (short*)alloc((size_t)QKVN * CHN * 2);
    short* woT    = (short*)alloc((size_t)CHN * CHN * 2);
    short* qkv    = (short*)alloc((size_t)NQROWS * QKVN * 2);
    short* hbuf   = (short*)alloc((size_t)NQROWS * CHN * 2);
    float* kvpart = (float*)alloc((size_t)16 * NCH * 2 * 128 * 64 * 4);
    float* kspart = (float*)alloc((size_t)16 * NCH * 128 * 4);
    short* kvt    = (short*)alloc((size_t)16 * 128 * 128 * 2);
    float* ksum   = (float*)alloc((size_t)16 * 128 * 4);

    // converts / transposes
    k_cvt<<<2048, 256, 0, stream>>>(x, xb, NQROWS * CHN / 4);
    k_transpose_cvt<<<dim3(QKVN / 32, CHN / 32), 256, 0, stream>>>(Wqkv, wqkvT, CHN, QKVN);
    k_transpose_cvt<<<dim3(CHN / 32, CHN / 32), 256, 0, stream>>>(Wo, woT, CHN, CHN);
    // GEMM1: qkv = xb @ Wqkv
    k_gemm_bt<0><<<(NQROWS / 128) * (QKVN / 128), 256, 0, stream>>>(
        xb, wqkvT, qkv, nullptr, nullptr, NQROWS, QKVN, CHN);
    // KV reduction (linear attention state)
    k_kvpart<<<16 * NCH * 2, 256, 0, stream>>>(qkv, kvpart, kspart);
    k_kvreduce<<<(16 * 128 * 128 + 16 * 128) / 256, 256, 0, stream>>>(kvpart, kspart, kvt, ksum);
    // fused middle -> h
    k_middle<<<16 * 128, 256, 0, stream>>>(qkv, kvt, ksum, conv_w, hbuf);
    // GEMM2 + residual: out = x + h @ Wo
    k_gemm_bt<1><<<(NQROWS / 128) * (CHN / 128), 256, 0, stream>>>(
        hbuf, woT, nullptr, out, x, NQROWS, CHN, CHN);
}